// Round 1
// baseline (367.780 us; speedup 1.0000x reference)
//
#include <hip/hip_runtime.h>
#include <hip/hip_bf16.h>
#include <math.h>

constexpr int C = 1000;
constexpr int B = 65536;
constexpr float SMOOTH = 0.1f;

__device__ inline float wave_reduce_max(float v) {
    #pragma unroll
    for (int off = 32; off > 0; off >>= 1)
        v = fmaxf(v, __shfl_xor(v, off, 64));
    return v;
}
__device__ inline float wave_reduce_sum(float v) {
    #pragma unroll
    for (int off = 32; off > 0; off >>= 1)
        v += __shfl_xor(v, off, 64);
    return v;
}

// Block reduce helpers for 256-thread blocks (4 waves)
__device__ inline float block_reduce_max(float v, float* sm) {
    v = wave_reduce_max(v);
    int wave = threadIdx.x >> 6, lane = threadIdx.x & 63;
    if (lane == 0) sm[wave] = v;
    __syncthreads();
    float r = fmaxf(fmaxf(sm[0], sm[1]), fmaxf(sm[2], sm[3]));
    __syncthreads();
    return r;
}
__device__ inline float block_reduce_sum(float v, float* sm) {
    v = wave_reduce_sum(v);
    int wave = threadIdx.x >> 6, lane = threadIdx.x & 63;
    if (lane == 0) sm[wave] = v;
    __syncthreads();
    float r = sm[0] + sm[1] + sm[2] + sm[3];
    __syncthreads();
    return r;
}

// Kernel 1: per class row t, compute smoothing row S[t,:] and its sum.
// S[t,j] = SMOOTH*(1 - A[t,j]) / (sum(A[t,:]) - A[t,t]);  S[t,t] = 1-SMOOTH
__global__ __launch_bounds__(256) void smooth_kernel(
        const float* __restrict__ ca, float* __restrict__ S,
        float* __restrict__ Srow) {
    __shared__ float sm[4];
    __shared__ float diag_sh;
    int t = blockIdx.x;
    int tid = threadIdx.x;
    const float* row = ca + (size_t)t * C;

    float v[4];
    float m = -INFINITY;
    #pragma unroll
    for (int k = 0; k < 4; k++) {
        int j = tid + k * 256;
        v[k] = (j < C) ? row[j] : -INFINITY;
        m = fmaxf(m, v[k]);
    }
    m = block_reduce_max(m, sm);

    float a[4];
    float zl = 0.f;
    #pragma unroll
    for (int k = 0; k < 4; k++) {
        int j = tid + k * 256;
        a[k] = (j < C) ? __expf(v[k] - m) : 0.f;
        zl += a[k];
    }
    float z = block_reduce_sum(zl, sm);
    float inv_z = 1.0f / z;

    float sumA_l = 0.f;
    #pragma unroll
    for (int k = 0; k < 4; k++) {
        a[k] *= inv_z;
        sumA_l += a[k];
        int j = tid + k * 256;
        if (j == t) diag_sh = a[k];   // visible after next __syncthreads (in reduce)
    }
    float sumA = block_reduce_sum(sumA_l, sm);

    float sums = sumA - diag_sh;
    float coef = SMOOTH / sums;
    float* Srt = S + (size_t)t * C;
    float srow_l = 0.f;
    #pragma unroll
    for (int k = 0; k < 4; k++) {
        int j = tid + k * 256;
        if (j < C) {
            float s = (j == t) ? (1.0f - SMOOTH) : (1.0f - a[k]) * coef;
            Srt[j] = s;
            srow_l += s;
        }
    }
    float srow = block_reduce_sum(srow_l, sm);
    if (tid == 0) Srow[t] = srow;
}

// Kernel 2: one wave per sample (grid-stride).
// loss_b = (m + log Z) * Srow[t]  -  dot(S[t,:], x[b,:])
__global__ __launch_bounds__(256) void loss_kernel(
        const float* __restrict__ x, const float* __restrict__ S,
        const float* __restrict__ Srow, const int* __restrict__ tgt,
        float* __restrict__ out) {
    int wave = threadIdx.x >> 6, lane = threadIdx.x & 63;
    int wgid = blockIdx.x * 4 + wave;
    int nw = gridDim.x * 4;
    float acc = 0.f;

    for (int b = wgid; b < B; b += nw) {
        int t = tgt[b];
        const float4* xr = (const float4*)(x + (size_t)b * C);
        const float4* sr = (const float4*)(S + (size_t)t * C);
        // 250 float4 per row: lane handles idx = lane + 64k, k=0..3 (k=3 partial)
        float4 xv[4], sv[4];
        #pragma unroll
        for (int k = 0; k < 3; k++) {
            xv[k] = xr[lane + k * 64];
            sv[k] = sr[lane + k * 64];
        }
        bool last = (lane + 192) < 250;
        if (last) {
            xv[3] = xr[lane + 192];
            sv[3] = sr[lane + 192];
        } else {
            xv[3] = make_float4(-INFINITY, -INFINITY, -INFINITY, -INFINITY);
            sv[3] = make_float4(0.f, 0.f, 0.f, 0.f);
        }

        float m = -INFINITY;
        #pragma unroll
        for (int k = 0; k < 4; k++)
            m = fmaxf(m, fmaxf(fmaxf(xv[k].x, xv[k].y), fmaxf(xv[k].z, xv[k].w)));
        m = wave_reduce_max(m);

        float zl = 0.f, dl = 0.f;
        #pragma unroll
        for (int k = 0; k < 4; k++) {
            // exp(-inf - m) = 0 for the padded lanes -> safe to include
            zl += __expf(xv[k].x - m) + __expf(xv[k].y - m) +
                  __expf(xv[k].z - m) + __expf(xv[k].w - m);
        }
        #pragma unroll
        for (int k = 0; k < 3; k++) {
            dl = fmaf(sv[k].x, xv[k].x, dl);
            dl = fmaf(sv[k].y, xv[k].y, dl);
            dl = fmaf(sv[k].z, xv[k].z, dl);
            dl = fmaf(sv[k].w, xv[k].w, dl);
        }
        if (last) {   // avoid 0 * -inf = NaN on padded lanes
            dl = fmaf(sv[3].x, xv[3].x, dl);
            dl = fmaf(sv[3].y, xv[3].y, dl);
            dl = fmaf(sv[3].z, xv[3].z, dl);
            dl = fmaf(sv[3].w, xv[3].w, dl);
        }
        float z = wave_reduce_sum(zl);
        float d = wave_reduce_sum(dl);
        float ss = Srow[t];
        float lb = (m + __logf(z)) * ss - d;
        acc += lb;   // same value on all 64 lanes
    }

    __shared__ float wacc[4];
    if (lane == 0) wacc[wave] = acc;
    __syncthreads();
    if (threadIdx.x == 0) {
        float tot = wacc[0] + wacc[1] + wacc[2] + wacc[3];
        atomicAdd(out, tot * (1.0f / (float)B));
    }
}

extern "C" void kernel_launch(void* const* d_in, const int* in_sizes, int n_in,
                              void* d_out, int out_size, void* d_ws, size_t ws_size,
                              hipStream_t stream) {
    const float* x   = (const float*)d_in[0];
    const float* ca  = (const float*)d_in[1];
    const int*   tgt = (const int*)d_in[2];
    float* out = (float*)d_out;

    float* S    = (float*)d_ws;                 // C*C floats = 4 MB
    float* Srow = S + (size_t)C * C;            // C floats

    hipMemsetAsync(out, 0, sizeof(float), stream);
    smooth_kernel<<<C, 256, 0, stream>>>(ca, S, Srow);
    loss_kernel<<<4096, 256, 0, stream>>>(x, S, Srow, tgt, out);
}

// Round 2
// 342.270 us; speedup vs baseline: 1.0745x; 1.0745x over previous
//
#include <hip/hip_runtime.h>
#include <hip/hip_bf16.h>
#include <math.h>

constexpr int C = 1000;
constexpr int B = 65536;
constexpr float SMOOTH = 0.1f;
constexpr int NBLK = B / 4;   // 4 waves per block, 1 sample per wave

typedef float f4 __attribute__((ext_vector_type(4)));

__device__ inline float wave_reduce_max(float v) {
    #pragma unroll
    for (int off = 32; off > 0; off >>= 1)
        v = fmaxf(v, __shfl_xor(v, off, 64));
    return v;
}
__device__ inline float wave_reduce_sum(float v) {
    #pragma unroll
    for (int off = 32; off > 0; off >>= 1)
        v += __shfl_xor(v, off, 64);
    return v;
}

__device__ inline float block_reduce_max(float v, float* sm) {
    v = wave_reduce_max(v);
    int wave = threadIdx.x >> 6, lane = threadIdx.x & 63;
    if (lane == 0) sm[wave] = v;
    __syncthreads();
    float r = fmaxf(fmaxf(sm[0], sm[1]), fmaxf(sm[2], sm[3]));
    __syncthreads();
    return r;
}
__device__ inline float block_reduce_sum(float v, float* sm) {
    v = wave_reduce_sum(v);
    int wave = threadIdx.x >> 6, lane = threadIdx.x & 63;
    if (lane == 0) sm[wave] = v;
    __syncthreads();
    float r = sm[0] + sm[1] + sm[2] + sm[3];
    __syncthreads();
    return r;
}

// Kernel 1: per class row t: A = softmax(row), S[t,j] = 0.1*(1-A)/ (sumA - A[t,t]),
// S[t,t] = 0.9; also Srow[t] = sum_j S[t,j].
__global__ __launch_bounds__(256) void smooth_kernel(
        const float* __restrict__ ca, float* __restrict__ S,
        float* __restrict__ Srow) {
    __shared__ float sm[4];
    __shared__ float diag_sh;
    int t = blockIdx.x;
    int tid = threadIdx.x;
    const float* row = ca + (size_t)t * C;

    float v[4];
    float m = -INFINITY;
    #pragma unroll
    for (int k = 0; k < 4; k++) {
        int j = tid + k * 256;
        v[k] = (j < C) ? row[j] : -INFINITY;
        m = fmaxf(m, v[k]);
    }
    m = block_reduce_max(m, sm);

    float a[4];
    float zl = 0.f;
    #pragma unroll
    for (int k = 0; k < 4; k++) {
        int j = tid + k * 256;
        a[k] = (j < C) ? __expf(v[k] - m) : 0.f;
        zl += a[k];
    }
    float z = block_reduce_sum(zl, sm);
    float inv_z = 1.0f / z;

    float sumA_l = 0.f;
    #pragma unroll
    for (int k = 0; k < 4; k++) {
        a[k] *= inv_z;
        sumA_l += a[k];
        int j = tid + k * 256;
        if (j == t) diag_sh = a[k];   // visible after syncthreads inside next reduce
    }
    float sumA = block_reduce_sum(sumA_l, sm);

    float sums = sumA - diag_sh;
    float coef = SMOOTH / sums;
    float* Srt = S + (size_t)t * C;
    float srow_l = 0.f;
    #pragma unroll
    for (int k = 0; k < 4; k++) {
        int j = tid + k * 256;
        if (j < C) {
            float s = (j == t) ? (1.0f - SMOOTH) : (1.0f - a[k]) * coef;
            Srt[j] = s;
            srow_l += s;
        }
    }
    float srow = block_reduce_sum(srow_l, sm);
    if (tid == 0) Srow[t] = srow;
}

// Kernel 2: one wave per sample, exactly one sample per wave.
// loss_b = (m + log Z) * Srow[t]  -  dot(S[t,:], x[b,:])
// Per-block partial written to d_ws (no atomics -> deterministic).
__global__ __launch_bounds__(256) void loss_kernel(
        const float* __restrict__ x, const float* __restrict__ S,
        const float* __restrict__ Srow, const int* __restrict__ tgt,
        float* __restrict__ partials) {
    int wave = threadIdx.x >> 6, lane = threadIdx.x & 63;
    int b = blockIdx.x * 4 + wave;          // B == 4*gridDim.x exactly

    int t = tgt[b];
    float ss = Srow[t];                      // issue early, used at the end
    const f4* xr = (const f4*)(x + (size_t)b * C);
    const f4* sr = (const f4*)(S + (size_t)t * C);

    // 250 f4 per row: lane handles idx = lane + 64k, k=0..3 (k=3 partial)
    f4 xv[4], sv[4];
    #pragma unroll
    for (int k = 0; k < 3; k++) {
        xv[k] = __builtin_nontemporal_load(xr + lane + k * 64);  // x streams once
        sv[k] = sr[lane + k * 64];                               // S: keep in L2
    }
    bool last = (lane + 192) < 250;
    if (last) {
        xv[3] = __builtin_nontemporal_load(xr + lane + 192);
        sv[3] = sr[lane + 192];
    } else {
        xv[3] = f4{-INFINITY, -INFINITY, -INFINITY, -INFINITY};
        sv[3] = f4{0.f, 0.f, 0.f, 0.f};
    }

    float m = -INFINITY;
    #pragma unroll
    for (int k = 0; k < 4; k++)
        m = fmaxf(m, fmaxf(fmaxf(xv[k].x, xv[k].y), fmaxf(xv[k].z, xv[k].w)));
    m = wave_reduce_max(m);

    float zl = 0.f, dl = 0.f;
    #pragma unroll
    for (int k = 0; k < 4; k++) {
        // exp(-inf - m) = 0 on padded lanes -> safe to include
        zl += __expf(xv[k].x - m) + __expf(xv[k].y - m) +
              __expf(xv[k].z - m) + __expf(xv[k].w - m);
    }
    #pragma unroll
    for (int k = 0; k < 3; k++) {
        dl = fmaf(sv[k].x, xv[k].x, dl);
        dl = fmaf(sv[k].y, xv[k].y, dl);
        dl = fmaf(sv[k].z, xv[k].z, dl);
        dl = fmaf(sv[k].w, xv[k].w, dl);
    }
    if (last) {   // avoid 0 * -inf = NaN on padded lanes
        dl = fmaf(sv[3].x, xv[3].x, dl);
        dl = fmaf(sv[3].y, xv[3].y, dl);
        dl = fmaf(sv[3].z, xv[3].z, dl);
        dl = fmaf(sv[3].w, xv[3].w, dl);
    }
    float z = wave_reduce_sum(zl);
    float d = wave_reduce_sum(dl);
    float lb = (m + __logf(z)) * ss - d;

    __shared__ float wacc[4];
    if (lane == 0) wacc[wave] = lb;
    __syncthreads();
    if (threadIdx.x == 0)
        partials[blockIdx.x] = wacc[0] + wacc[1] + wacc[2] + wacc[3];
}

// Kernel 3: sum NBLK partials -> out = sum / B. Single block, deterministic.
__global__ __launch_bounds__(256) void reduce_kernel(
        const float* __restrict__ partials, float* __restrict__ out) {
    __shared__ float sm[4];
    const f4* p4 = (const f4*)partials;      // NBLK/4 = 4096 f4 = 256 threads * 16
    float s = 0.f;
    #pragma unroll
    for (int k = 0; k < 16; k++) {
        f4 v = p4[threadIdx.x + k * 256];
        s += (v.x + v.y) + (v.z + v.w);
    }
    s = block_reduce_sum(s, sm);
    if (threadIdx.x == 0) out[0] = s * (1.0f / (float)B);
}

extern "C" void kernel_launch(void* const* d_in, const int* in_sizes, int n_in,
                              void* d_out, int out_size, void* d_ws, size_t ws_size,
                              hipStream_t stream) {
    const float* x   = (const float*)d_in[0];
    const float* ca  = (const float*)d_in[1];
    const int*   tgt = (const int*)d_in[2];
    float* out = (float*)d_out;

    float* S        = (float*)d_ws;                  // C*C floats = 4 MB
    float* Srow     = S + (size_t)C * C;             // C floats
    float* partials = Srow + C;                      // NBLK floats = 64 KB

    smooth_kernel<<<C, 256, 0, stream>>>(ca, S, Srow);
    loss_kernel<<<NBLK, 256, 0, stream>>>(x, S, Srow, tgt, partials);
    reduce_kernel<<<1, 256, 0, stream>>>(partials, out);
}